// Round 16
// baseline (366.066 us; speedup 1.0000x reference)
//
#include <hip/hip_runtime.h>
#include <cstdint>
#include <cstddef>
#include <cstring>

// Problem constants
#define BB 8
#define TT 1024
#define CC 768
#define NH 12
#define HD 64
// GEMM1: M=8192 N=2304 K=768.  GEMM2: M=8192 N=768 K=768.

using bf16x8 = __attribute__((ext_vector_type(8))) short;  // 8 bf16 (4 VGPRs)
using f32x4  = __attribute__((ext_vector_type(4))) float;  // 4 fp32

static __device__ __forceinline__ short f2bf(float f) {
    uint32_t u;
    __builtin_memcpy(&u, &f, 4);
    u += 0x7FFFu + ((u >> 16) & 1u);   // RNE
    return (short)(u >> 16);
}

static __device__ __forceinline__ uint32_t bfpack(float lo, float hi) {
    return (uint32_t)(uint16_t)f2bf(lo) | ((uint32_t)(uint16_t)f2bf(hi) << 16);
}

// ---------------------------------------------------------------- merged prep
// bid ranges: [0,1728) Wqkv transpose | [1728,2304) Wproj transpose |
// [2304,5376) x cast | [5376,5504) fc table.
__global__ __launch_bounds__(256)
void prep_kernel(const float* __restrict__ x, const float* __restrict__ Wqkv,
                 const float* __restrict__ Wproj,
                 short* __restrict__ WqkvT, short* __restrict__ WprojT,
                 short* __restrict__ xb, float2* __restrict__ fc) {
    __shared__ float tile[32][33];
    const int tid = threadIdx.x;
    int bid = blockIdx.x;
    if (bid < 2304) {
        const float* in;
        short* out;
        int Cdim, bx, by;
        if (bid < 1728) { in = Wqkv; out = WqkvT; Cdim = 2304; bx = bid % 72; by = bid / 72; }
        else { int b2 = bid - 1728; in = Wproj; out = WprojT; Cdim = 768; bx = b2 % 24; by = b2 / 24; }
        int tx = tid & 31, ty = tid >> 5;
        int c0 = bx * 32, r0 = by * 32;
#pragma unroll
        for (int i = 0; i < 4; i++)
            tile[ty + 8 * i][tx] = in[(size_t)(r0 + ty + 8 * i) * Cdim + c0 + tx];
        __syncthreads();
#pragma unroll
        for (int i = 0; i < 4; i++)
            out[(size_t)(c0 + ty + 8 * i) * 768 + r0 + tx] = f2bf(tile[tx][ty + 8 * i]);
    } else if (bid < 5376) {
        int i = ((bid - 2304) * 256 + tid) * 8;
        float4 f0 = *(const float4*)(x + i);
        float4 f1 = *(const float4*)(x + i + 4);
        bf16x8 h;
        h[0] = f2bf(f0.x); h[1] = f2bf(f0.y); h[2] = f2bf(f0.z); h[3] = f2bf(f0.w);
        h[4] = f2bf(f1.x); h[5] = f2bf(f1.y); h[6] = f2bf(f1.z); h[7] = f2bf(f1.w);
        *(bf16x8*)(xb + i) = h;
    } else {
        int idx = (bid - 5376) * 256 + tid;   // 32768 = 1024*32
        int t = idx >> 5, p = idx & 31;
        float freq = powf(10000.0f, -(float)p / 32.0f);
        float a = (float)t * freq;
        fc[idx] = make_float2(cosf(a), sinf(a));
    }
}

// ---------------------------------------------------------------- A-LDS / B-direct GEMM
// r16 single-variable test: stage ONLY A in LDS (2x16KB dbuf = 32 KB for EPI0 ->
// 4 blocks/CU, 16 waves/CU); load B-fragments DIRECTLY from global BT[n][k]
// each K-step (attn-style 16-row x 16B gather; B panel is L2-resident per XCD).
// Halves per-phase staging + barrier-protected data; tests whether the ~4700cyc
// phase invariant is a latency equilibrium (more TLP -> faster) or intrinsic.
// EPI1 (GEMM2) keeps 64 KB LDS for its fp32 repack (2 blocks/CU as before).
template <int EPI>
__global__ __launch_bounds__(256, EPI == 0 ? 4 : 2)
void gemm_kernel(const short* __restrict__ Agl, const short* __restrict__ BT,
                 const float* __restrict__ bias,
                 short* __restrict__ Qb, short* __restrict__ Kb, short* __restrict__ VT,
                 const float2* __restrict__ fc, float* __restrict__ out) {
    __shared__ __align__(16) char smem_c[EPI == 0 ? 32768 : 65536];
    short (*As)[128 * 64] = (short(*)[128 * 64])smem_c;   // 2 bufs x 16 KB
    const int tid = threadIdx.x;
    const int lane = tid & 63, wid = tid >> 6;
    const int g = lane >> 4, c = lane & 15;
    const int wm = wid >> 1, wn = wid & 1;

    // bijective XCD swizzle (nwg % 8 == 0: 1152 and 384)
    const int nx = gridDim.x;
    const int bid = blockIdx.y * nx + blockIdx.x;
    const int cpx = (nx * gridDim.y) >> 3;
    const int swz = (bid & 7) * cpx + (bid >> 3);
    const int m0 = (swz / nx) * 128, n0 = (swz % nx) * 128;

    const int srow = lane >> 2;       // 0..15
    const int sch = lane & 3;
    const short* Ab0 = Agl + (size_t)(m0 + wid * 32 + srow) * 768 + sch * 8;
    // B fragment base: row n0 + wn*64 + ni*16 + c, col kt*64 + kk*32 + g*8
    const short* Bw = BT + (size_t)(n0 + wn * 64 + c) * 768 + g * 8;

    const f32x4 zero4 = {0.f, 0.f, 0.f, 0.f};
    f32x4 acc[4][4];
#pragma unroll
    for (int i = 0; i < 4; i++)
#pragma unroll
        for (int j = 0; j < 4; j++) acc[i][j] = zero4;

    bf16x8 rA[4], rBf[8];
#define LOADA(kt)                                                              \
    {                                                                          \
        size_t ko = (size_t)(kt) * 64;                                         \
        _Pragma("unroll")                                                      \
        for (int q = 0; q < 2; q++)                                            \
            _Pragma("unroll")                                                  \
            for (int h = 0; h < 2; h++)                                        \
                rA[q * 2 + h] = *(const bf16x8*)(Ab0 + (size_t)q * 16 * 768 + ko + h * 32); \
    }
#define WRITEA(buf)                                                            \
    {                                                                          \
        _Pragma("unroll")                                                      \
        for (int q = 0; q < 2; q++)                                            \
            _Pragma("unroll")                                                  \
            for (int h = 0; h < 2; h++) {                                      \
                int row = wid * 32 + q * 16 + srow;                            \
                int ci = sch + h * 4;                                          \
                *(bf16x8*)&As[buf][row * 64 + ((ci ^ (row & 7)) * 8)] = rA[q * 2 + h]; \
            }                                                                  \
    }
#define LOADB(kt)                                                              \
    {                                                                          \
        _Pragma("unroll")                                                      \
        for (int kk2 = 0; kk2 < 2; kk2++)                                      \
            _Pragma("unroll")                                                  \
            for (int ni = 0; ni < 4; ni++)                                     \
                rBf[kk2 * 4 + ni] = *(const bf16x8*)(Bw + (size_t)ni * 16 * 768 + \
                                                     (size_t)(kt) * 64 + kk2 * 32); \
    }
#define COMPUTE(buf)                                                           \
    {                                                                          \
        _Pragma("unroll")                                                      \
        for (int kk = 0; kk < 2; kk++) {                                       \
            bf16x8 af[4];                                                      \
            _Pragma("unroll")                                                  \
            for (int mi = 0; mi < 4; mi++) {                                   \
                int row = wm * 64 + mi * 16 + c;                               \
                af[mi] = *(const bf16x8*)&As[buf][row * 64 + (((kk * 4 + g) ^ (row & 7)) * 8)]; \
            }                                                                  \
            __builtin_amdgcn_s_setprio(1);                                     \
            _Pragma("unroll")                                                  \
            for (int mi = 0; mi < 4; mi++)                                     \
                _Pragma("unroll")                                              \
                for (int ni = 0; ni < 4; ni++)                                 \
                    acc[mi][ni] = __builtin_amdgcn_mfma_f32_16x16x32_bf16(     \
                        af[mi], rBf[kk * 4 + ni], acc[mi][ni], 0, 0, 0);       \
            __builtin_amdgcn_s_setprio(0);                                     \
        }                                                                      \
    }

    // prologue: A tile0 -> buf0
    LOADA(0);
    WRITEA(0);
    __syncthreads();

#pragma unroll 1
    for (int t2 = 0; t2 < 12; t2 += 2) {
        // tile t2 (buf0): A(t2+1) issued early; B(t2) direct; compute; swap
        LOADA(t2 + 1);
        LOADB(t2);
        COMPUTE(0);
        __syncthreads();
        WRITEA(1);
        __syncthreads();
        if (t2 + 2 < 12) {
            LOADA(t2 + 2);
            LOADB(t2 + 1);
            COMPUTE(1);
            __syncthreads();
            WRITEA(0);
            __syncthreads();
        } else {
            LOADB(t2 + 1);
            COMPUTE(1);
        }
    }
    __syncthreads();   // all waves done with LDS before epilogue reuse

    if (EPI == 0) {
        uint32_t* LD = (uint32_t*)smem_c;   // 32 KB
#pragma unroll
        for (int ni = 0; ni < 4; ni++) {
            int nl = wn * 64 + ni * 16 + c;
            int n = n0 + nl;
            float bv = bias[n];
            int part = (n >= 1536) ? 2 : (n >= 768 ? 1 : 0);
            int d = (n - part * 768) & 63;
#pragma unroll
            for (int mi = 0; mi < 4; mi++) {
#pragma unroll
                for (int r = 0; r < 4; r++) {
                    int ml = wm * 64 + mi * 16 + g * 4 + r;
                    float v = acc[mi][ni][r] + bv;
                    float pv = __shfl_xor(v, 1);
                    if (!(c & 1)) {
                        float o0, o1;
                        if (part < 2) {
                            int t = (m0 + ml) & 1023;
                            float2 cs = fc[t * 32 + (d >> 1)];
                            o0 = v * cs.x - pv * cs.y;
                            o1 = v * cs.y + pv * cs.x;
                            if (part == 0) { o0 *= 0.125f; o1 *= 0.125f; }
                        } else { o0 = v; o1 = pv; }
                        LD[ml * 64 + ((nl >> 1) ^ (((ml >> 2) & 3) << 3))] = bfpack(o0, o1);
                    }
                }
            }
        }
        __syncthreads();
        if (n0 >= 1536) {
            int n0r = n0 - 1536;
            int h0 = n0r >> 6;
            int wc = tid & 63;
            int seg = tid >> 2 >> 4;
            int h = h0 + (wc >> 5);
            int d0 = (2 * wc) & 63;
            int b = m0 >> 10, t0r = m0 & 1023;
            uint32_t wlo[16], whi[16];
#pragma unroll
            for (int j2 = 0; j2 < 16; j2++) {
                int mlA = seg * 32 + 2 * j2;
                int mlB = mlA + 1;
                uint32_t wa = LD[mlA * 64 + (wc ^ (((mlA >> 2) & 3) << 3))];
                uint32_t wb = LD[mlB * 64 + (wc ^ (((mlB >> 2) & 3) << 3))];
                wlo[j2] = (wa & 0xFFFFu) | (wb << 16);
                whi[j2] = (wa >> 16) | (wb & 0xFFFF0000u);
            }
            short* p0 = VT + ((size_t)(b * NH + h) * HD + d0) * TT + t0r + seg * 32;
            short* p1 = p0 + TT;
#pragma unroll
            for (int k = 0; k < 4; k++) {
                int4 v0, v1;
                __builtin_memcpy(&v0, &wlo[k * 4], 16);
                __builtin_memcpy(&v1, &whi[k * 4], 16);
                *(int4*)(p0 + k * 8) = v0;
                *(int4*)(p1 + k * 8) = v1;
            }
        } else {
#pragma unroll
            for (int p = 0; p < 8; p++) {
                int ml = p * 16 + (tid >> 4);
                int wc = (tid & 15) * 4;
                int4 dat = *(const int4*)&LD[ml * 64 + (wc ^ (((ml >> 2) & 3) << 3))];
                int n = n0 + wc * 2;
                int part = (n >= 768) ? 1 : 0;
                int rem = n - part * 768;
                int h = rem >> 6, d = rem & 63;
                int m = m0 + ml, b = m >> 10, t = m & 1023;
                short* dst = (part == 0 ? Qb : Kb)
                             + (((size_t)b * NH + h) * TT + t) * HD + d;
                *(int4*)dst = dat;
            }
        }
    } else {
        float* LDf = (float*)smem_c;   // 64 KB
#pragma unroll
        for (int mi = 0; mi < 4; mi++)
#pragma unroll
            for (int ni = 0; ni < 4; ni++) {
                int nl = wn * 64 + ni * 16 + c;
                float bv = bias[n0 + nl];
#pragma unroll
                for (int r = 0; r < 4; r++) {
                    int ml = wm * 64 + mi * 16 + g * 4 + r;
                    LDf[ml * 128 + (nl ^ (r << 3))] = acc[mi][ni][r] + bv;
                }
            }
        __syncthreads();
#pragma unroll
        for (int p = 0; p < 8; p++) {
            int ml = p * 16 + (tid >> 4);
            int rr = (ml & 3) << 3;
            int wc4 = (tid & 15) * 8;
            const float* rp = &LDf[ml * 128 + (wc4 ^ rr)];
            float4 f0 = *(const float4*)rp;
            float4 f1 = *(const float4*)(rp + 4);
            float* dst = out + (size_t)(m0 + ml) * CC + n0 + wc4;
            *(float4*)dst = f0;
            *(float4*)(dst + 4) = f1;
        }
    }
#undef LOADA
#undef WRITEA
#undef LOADB
#undef COMPUTE
}

// ---------------------------------------------------------------- flash attention
// (byte-identical to r15 — passed; swapped-operand S^T = mfma(K,Q), lane-local
// softmax, per-wave barrier-free LDS P-tile, V from global VT, setprio on MFMA,
// LDS O^T epilogue)
__global__ __launch_bounds__(256)
void attn_kernel(const short* __restrict__ Qb, const short* __restrict__ Kb,
                 const short* __restrict__ VT, short* __restrict__ Ob) {
    __shared__ uint32_t Pt[4][32][32];  // 16 KB per-wave P tile, XOR-swizzled
    __shared__ uint32_t ot[128 * 32];   // 16 KB epilogue O^T transpose
    const int tid = threadIdx.x, lane = tid & 63, wid = tid >> 6;
    const int g = lane >> 4, c = lane & 15;
    const int bh = blockIdx.x, qb = 7 - (int)blockIdx.y;
    const int b = bh / NH, h = bh % NH;
    const short* Qp = Qb + (size_t)bh * TT * HD;
    const short* Kp = Kb + (size_t)bh * TT * HD;
    const short* Vp = VT + (size_t)bh * TT * HD;
    const int q0 = qb * 128 + wid * 32;
    const int sw = (c & 7) << 2;

    bf16x8 qf[2][2];
#pragma unroll
    for (int qs = 0; qs < 2; qs++)
#pragma unroll
        for (int kh = 0; kh < 2; kh++)
            qf[qs][kh] = *(const bf16x8*)(Qp + (size_t)(q0 + qs * 16 + c) * HD + kh * 32 + g * 8);

    const f32x4 zero4 = {0.f, 0.f, 0.f, 0.f};
    f32x4 o[2][4];
#pragma unroll
    for (int qs = 0; qs < 2; qs++)
#pragma unroll
        for (int dt = 0; dt < 4; dt++) o[qs][dt] = zero4;
    float mrun[2] = {-1e30f, -1e30f}, lrun[2] = {0.f, 0.f};

    const int t0max = ((q0 + 31) >> 6) << 6;
    for (int t0 = 0; t0 <= t0max; t0 += 64) {
        f32x4 st[2][4];
#pragma unroll
        for (int nt = 0; nt < 4; nt++) {
            const short* kp = Kp + (size_t)(t0 + nt * 16 + c) * HD + g * 8;
            bf16x8 k0 = *(const bf16x8*)kp;
            bf16x8 k1 = *(const bf16x8*)(kp + 32);
#pragma unroll
            for (int qs = 0; qs < 2; qs++) {
                f32x4 z = zero4;
                __builtin_amdgcn_s_setprio(1);
                z = __builtin_amdgcn_mfma_f32_16x16x32_bf16(k0, qf[qs][0], z, 0, 0, 0);
                z = __builtin_amdgcn_mfma_f32_16x16x32_bf16(k1, qf[qs][1], z, 0, 0, 0);
                __builtin_amdgcn_s_setprio(0);
                st[qs][nt] = z;
            }
        }
        bf16x8 vf[2][4];
#pragma unroll
        for (int blk = 0; blk < 2; blk++)
#pragma unroll
            for (int dt = 0; dt < 4; dt++)
                vf[blk][dt] = *(const bf16x8*)(Vp + (size_t)(dt * 16 + c) * TT + t0 + blk * 32 + g * 8);
        if (t0 + 63 > q0) {
#pragma unroll
            for (int qs = 0; qs < 2; qs++) {
                int q = q0 + qs * 16 + c;
#pragma unroll
                for (int nt = 0; nt < 4; nt++)
#pragma unroll
                    for (int r = 0; r < 4; r++)
                        if (t0 + nt * 16 + g * 4 + r > q) st[qs][nt][r] = -1e30f;
            }
        }
#pragma unroll
        for (int qs = 0; qs < 2; qs++) {
            float mx = st[qs][0][0];
#pragma unroll
            for (int nt = 0; nt < 4; nt++)
#pragma unroll
                for (int r = 0; r < 4; r++) mx = fmaxf(mx, st[qs][nt][r]);
            mx = fmaxf(mx, __shfl_xor(mx, 16));
            mx = fmaxf(mx, __shfl_xor(mx, 32));
            float mnew = fmaxf(mrun[qs], mx);
            float al = __expf(mrun[qs] - mnew);
            mrun[qs] = mnew;
            float sm = 0.f;
#pragma unroll
            for (int nt = 0; nt < 4; nt++)
#pragma unroll
                for (int r = 0; r < 4; r++) {
                    float e = __expf(st[qs][nt][r] - mnew);
                    st[qs][nt][r] = e;
                    sm += e;
                }
            sm += __shfl_xor(sm, 16);
            sm += __shfl_xor(sm, 32);
            lrun[qs] = lrun[qs] * al + sm;
#pragma unroll
            for (int dt = 0; dt < 4; dt++) {
                o[qs][dt][0] *= al; o[qs][dt][1] *= al;
                o[qs][dt][2] *= al; o[qs][dt][3] *= al;
            }
            int row = qs * 16 + c;
#pragma unroll
            for (int nt = 0; nt < 4; nt++) {
                uint32_t w0 = bfpack(st[qs][nt][0], st[qs][nt][1]);
                uint32_t w1 = bfpack(st[qs][nt][2], st[qs][nt][3]);
                int wa = nt * 8 + 2 * g;
                Pt[wid][row][wa ^ sw]       = w0;
                Pt[wid][row][(wa + 1) ^ sw] = w1;
            }
        }
#pragma unroll
        for (int qs = 0; qs < 2; qs++) {
            int row = qs * 16 + c;
#pragma unroll
            for (int blk = 0; blk < 2; blk++) {
                bf16x8 pf = *(const bf16x8*)&Pt[wid][row][(blk * 16 + 4 * g) ^ sw];
                __builtin_amdgcn_s_setprio(1);
#pragma unroll
                for (int dt = 0; dt < 4; dt++)
                    o[qs][dt] = __builtin_amdgcn_mfma_f32_16x16x32_bf16(
                        vf[blk][dt], pf, o[qs][dt], 0, 0, 0);
                __builtin_amdgcn_s_setprio(0);
            }
        }
    }

#pragma unroll
    for (int qs = 0; qs < 2; qs++) {
        float inv = 1.0f / lrun[qs];
        int ql = wid * 32 + qs * 16 + c;
#pragma unroll
        for (int dt = 0; dt < 4; dt++) {
            uint32_t w0 = bfpack(o[qs][dt][0] * inv, o[qs][dt][1] * inv);
            uint32_t w1 = bfpack(o[qs][dt][2] * inv, o[qs][dt][3] * inv);
            int jc0 = dt * 8 + 2 * g;
            int jc1 = jc0 + 1;
            ot[ql * 32 + ((((jc0 >> 2) ^ (c & 7)) << 2) | (jc0 & 3))] = w0;
            ot[ql * 32 + ((((jc1 >> 2) ^ (c & 7)) << 2) | (jc1 & 3))] = w1;
        }
    }
    __syncthreads();
#pragma unroll
    for (int p = 0; p < 4; p++) {
        int q = (tid >> 3) + 32 * p;
        int jb = tid & 7;
        const uint32_t* src = &ot[q * 32 + ((jb ^ (q & 7)) << 2)];
        int4 w = *(const int4*)src;
        *(int4*)(Ob + ((size_t)b * TT + qb * 128 + q) * CC + h * HD + jb * 8) = w;
    }
}

// ---------------------------------------------------------------- launch
extern "C" void kernel_launch(void* const* d_in, const int* in_sizes, int n_in,
                              void* d_out, int out_size, void* d_ws, size_t ws_size,
                              hipStream_t stream) {
    const float* x     = (const float*)d_in[0];
    const float* Wqkv  = (const float*)d_in[1];
    const float* bqkv  = (const float*)d_in[2];
    const float* Wproj = (const float*)d_in[3];
    const float* bproj = (const float*)d_in[4];
    // d_in[5] = mask: causal by construction, unused

    char* ws = (char*)d_ws;
    short*  WqkvT  = (short*)(ws);
    short*  WprojT = (short*)(ws + 3538944);
    float2* fc     = (float2*)(ws + 3538944 + 1179648);
    short*  Qb     = (short*)(ws + 4980736);
    short*  Kb     = (short*)(ws + 4980736 + 1 * 12582912);
    short*  VOb    = (short*)(ws + 4980736 + 2 * 12582912);  // xb, then O after attn
    short*  VbT    = (short*)(ws + 4980736 + 3 * 12582912);
    short*  xb     = VOb;
    float*  out    = (float*)d_out;

    hipLaunchKernelGGL(prep_kernel, dim3(5504), dim3(256), 0, stream,
                       x, Wqkv, Wproj, WqkvT, WprojT, xb, fc);
    hipLaunchKernelGGL((gemm_kernel<0>), dim3(18, 64), dim3(256), 0, stream,
                       xb, WqkvT, bqkv, Qb, Kb, VbT, fc, (float*)nullptr);
    hipLaunchKernelGGL(attn_kernel, dim3(96, 8), dim3(256), 0, stream, Qb, Kb, VbT, VOb);
    hipLaunchKernelGGL((gemm_kernel<1>), dim3(6, 64), dim3(256), 0, stream,
                       VOb, WprojT, bproj,
                       (short*)nullptr, (short*)nullptr, (short*)nullptr,
                       (const float2*)nullptr, out);
}

// Round 17
// 163.395 us; speedup vs baseline: 2.2404x; 2.2404x over previous
//
#include <hip/hip_runtime.h>
#include <cstdint>
#include <cstddef>
#include <cstring>

// Problem constants
#define BB 8
#define TT 1024
#define CC 768
#define NH 12
#define HD 64
// GEMM1: M=8192 N=2304 K=768.  GEMM2: M=8192 N=768 K=768.

using bf16x8 = __attribute__((ext_vector_type(8))) short;  // 8 bf16 (4 VGPRs)
using f32x4  = __attribute__((ext_vector_type(4))) float;  // 4 fp32

static __device__ __forceinline__ short f2bf(float f) {
    uint32_t u;
    __builtin_memcpy(&u, &f, 4);
    u += 0x7FFFu + ((u >> 16) & 1u);   // RNE
    return (short)(u >> 16);
}

static __device__ __forceinline__ uint32_t bfpack(float lo, float hi) {
    return (uint32_t)(uint16_t)f2bf(lo) | ((uint32_t)(uint16_t)f2bf(hi) << 16);
}

// ---------------------------------------------------------------- merged prep
// bid ranges: [0,1728) Wqkv transpose | [1728,2304) Wproj transpose |
// [2304,5376) x cast | [5376,5504) fc table.
__global__ __launch_bounds__(256)
void prep_kernel(const float* __restrict__ x, const float* __restrict__ Wqkv,
                 const float* __restrict__ Wproj,
                 short* __restrict__ WqkvT, short* __restrict__ WprojT,
                 short* __restrict__ xb, float2* __restrict__ fc) {
    __shared__ float tile[32][33];
    const int tid = threadIdx.x;
    int bid = blockIdx.x;
    if (bid < 2304) {
        const float* in;
        short* out;
        int Cdim, bx, by;
        if (bid < 1728) { in = Wqkv; out = WqkvT; Cdim = 2304; bx = bid % 72; by = bid / 72; }
        else { int b2 = bid - 1728; in = Wproj; out = WprojT; Cdim = 768; bx = b2 % 24; by = b2 / 24; }
        int tx = tid & 31, ty = tid >> 5;
        int c0 = bx * 32, r0 = by * 32;
#pragma unroll
        for (int i = 0; i < 4; i++)
            tile[ty + 8 * i][tx] = in[(size_t)(r0 + ty + 8 * i) * Cdim + c0 + tx];
        __syncthreads();
#pragma unroll
        for (int i = 0; i < 4; i++)
            out[(size_t)(c0 + ty + 8 * i) * 768 + r0 + tx] = f2bf(tile[tx][ty + 8 * i]);
    } else if (bid < 5376) {
        int i = ((bid - 2304) * 256 + tid) * 8;
        float4 f0 = *(const float4*)(x + i);
        float4 f1 = *(const float4*)(x + i + 4);
        bf16x8 h;
        h[0] = f2bf(f0.x); h[1] = f2bf(f0.y); h[2] = f2bf(f0.z); h[3] = f2bf(f0.w);
        h[4] = f2bf(f1.x); h[5] = f2bf(f1.y); h[6] = f2bf(f1.z); h[7] = f2bf(f1.w);
        *(bf16x8*)(xb + i) = h;
    } else {
        int idx = (bid - 5376) * 256 + tid;   // 32768 = 1024*32
        int t = idx >> 5, p = idx & 31;
        float freq = powf(10000.0f, -(float)p / 32.0f);
        float a = (float)t * freq;
        fc[idx] = make_float2(cosf(a), sinf(a));
    }
}

// ---------------------------------------------------------------- reg-staged GEMM
// (r13 configuration — session best, 163.0 µs measured)
template <int EPI>
__global__ __launch_bounds__(256, 2)
void gemm_kernel(const short* __restrict__ Agl, const short* __restrict__ BT,
                 const float* __restrict__ bias,
                 short* __restrict__ Qb, short* __restrict__ Kb, short* __restrict__ VT,
                 const float2* __restrict__ fc, float* __restrict__ out) {
    __shared__ __align__(16) short smem_s[4 * 128 * 64];   // 64 KB
    short (*As)[128 * 64] = (short(*)[128 * 64])smem_s;
    short (*Bs)[128 * 64] = (short(*)[128 * 64])(smem_s + 2 * 128 * 64);
    const int tid = threadIdx.x;
    const int lane = tid & 63, wid = tid >> 6;
    const int g = lane >> 4, c = lane & 15;
    const int wm = wid >> 1, wn = wid & 1;

    const int nx = gridDim.x;
    const int bid = blockIdx.y * nx + blockIdx.x;
    const int cpx = (nx * gridDim.y) >> 3;
    const int swz = (bid & 7) * cpx + (bid >> 3);
    const int m0 = (swz / nx) * 128, n0 = (swz % nx) * 128;

    const int srow = lane >> 2;
    const int sch = lane & 3;
    const short* Ab0 = Agl + (size_t)(m0 + wid * 32 + srow) * 768 + sch * 8;
    const short* Bb0 = BT  + (size_t)(n0 + wid * 32 + srow) * 768 + sch * 8;

    const f32x4 zero4 = {0.f, 0.f, 0.f, 0.f};
    f32x4 acc[4][4];
#pragma unroll
    for (int i = 0; i < 4; i++)
#pragma unroll
        for (int j = 0; j < 4; j++) acc[i][j] = zero4;

    bf16x8 rA[4], rB[4];
#define LOAD(kt)                                                               \
    {                                                                          \
        size_t ko = (size_t)(kt) * 64;                                         \
        _Pragma("unroll")                                                      \
        for (int q = 0; q < 2; q++)                                            \
            _Pragma("unroll")                                                  \
            for (int h = 0; h < 2; h++) {                                      \
                rA[q * 2 + h] = *(const bf16x8*)(Ab0 + (size_t)q * 16 * 768 + ko + h * 32); \
                rB[q * 2 + h] = *(const bf16x8*)(Bb0 + (size_t)q * 16 * 768 + ko + h * 32); \
            }                                                                  \
    }
#define WRITE(buf)                                                             \
    {                                                                          \
        _Pragma("unroll")                                                      \
        for (int q = 0; q < 2; q++)                                            \
            _Pragma("unroll")                                                  \
            for (int h = 0; h < 2; h++) {                                      \
                int row = wid * 32 + q * 16 + srow;                            \
                int ci = sch + h * 4;                                          \
                int idx = row * 64 + ((ci ^ (row & 7)) * 8);                   \
                *(bf16x8*)&As[buf][idx] = rA[q * 2 + h];                       \
                *(bf16x8*)&Bs[buf][idx] = rB[q * 2 + h];                       \
            }                                                                  \
    }
#define COMPUTE(buf)                                                           \
    {                                                                          \
        _Pragma("unroll")                                                      \
        for (int kk = 0; kk < 2; kk++) {                                       \
            bf16x8 af[4], bfr[4];                                              \
            _Pragma("unroll")                                                  \
            for (int mi = 0; mi < 4; mi++) {                                   \
                int row = wm * 64 + mi * 16 + c;                               \
                af[mi] = *(const bf16x8*)&As[buf][row * 64 + (((kk * 4 + g) ^ (row & 7)) * 8)]; \
            }                                                                  \
            _Pragma("unroll")                                                  \
            for (int ni = 0; ni < 4; ni++) {                                   \
                int row = wn * 64 + ni * 16 + c;                               \
                bfr[ni] = *(const bf16x8*)&Bs[buf][row * 64 + (((kk * 4 + g) ^ (row & 7)) * 8)]; \
            }                                                                  \
            __builtin_amdgcn_s_setprio(1);                                     \
            _Pragma("unroll")                                                  \
            for (int mi = 0; mi < 4; mi++)                                     \
                _Pragma("unroll")                                              \
                for (int ni = 0; ni < 4; ni++)                                 \
                    acc[mi][ni] = __builtin_amdgcn_mfma_f32_16x16x32_bf16(     \
                        af[mi], bfr[ni], acc[mi][ni], 0, 0, 0);                \
            __builtin_amdgcn_s_setprio(0);                                     \
        }                                                                      \
    }

    LOAD(0);
    WRITE(0);
    __syncthreads();

#pragma unroll 1
    for (int t2 = 0; t2 < 12; t2 += 2) {
        LOAD(t2 + 1);
        COMPUTE(0);
        __syncthreads();
        WRITE(1);
        __syncthreads();
        if (t2 + 2 < 12) {
            LOAD(t2 + 2);
            COMPUTE(1);
            __syncthreads();
            WRITE(0);
            __syncthreads();
        } else {
            COMPUTE(1);
        }
    }
    __syncthreads();

    if (EPI == 0) {
        uint32_t* LD = (uint32_t*)smem_s;   // 32 KB
#pragma unroll
        for (int ni = 0; ni < 4; ni++) {
            int nl = wn * 64 + ni * 16 + c;
            int n = n0 + nl;
            float bv = bias[n];
            int part = (n >= 1536) ? 2 : (n >= 768 ? 1 : 0);
            int d = (n - part * 768) & 63;
#pragma unroll
            for (int mi = 0; mi < 4; mi++) {
#pragma unroll
                for (int r = 0; r < 4; r++) {
                    int ml = wm * 64 + mi * 16 + g * 4 + r;
                    float v = acc[mi][ni][r] + bv;
                    float pv = __shfl_xor(v, 1);
                    if (!(c & 1)) {
                        float o0, o1;
                        if (part < 2) {
                            int t = (m0 + ml) & 1023;
                            float2 cs = fc[t * 32 + (d >> 1)];
                            o0 = v * cs.x - pv * cs.y;
                            o1 = v * cs.y + pv * cs.x;
                            if (part == 0) { o0 *= 0.125f; o1 *= 0.125f; }
                        } else { o0 = v; o1 = pv; }
                        LD[ml * 64 + ((nl >> 1) ^ (((ml >> 2) & 3) << 3))] = bfpack(o0, o1);
                    }
                }
            }
        }
        __syncthreads();
        if (n0 >= 1536) {
            int n0r = n0 - 1536;
            int h0 = n0r >> 6;
            int wc = tid & 63;
            int seg = tid >> 2 >> 4;
            int h = h0 + (wc >> 5);
            int d0 = (2 * wc) & 63;
            int b = m0 >> 10, t0r = m0 & 1023;
            uint32_t wlo[16], whi[16];
#pragma unroll
            for (int j2 = 0; j2 < 16; j2++) {
                int mlA = seg * 32 + 2 * j2;
                int mlB = mlA + 1;
                uint32_t wa = LD[mlA * 64 + (wc ^ (((mlA >> 2) & 3) << 3))];
                uint32_t wb = LD[mlB * 64 + (wc ^ (((mlB >> 2) & 3) << 3))];
                wlo[j2] = (wa & 0xFFFFu) | (wb << 16);
                whi[j2] = (wa >> 16) | (wb & 0xFFFF0000u);
            }
            short* p0 = VT + ((size_t)(b * NH + h) * HD + d0) * TT + t0r + seg * 32;
            short* p1 = p0 + TT;
#pragma unroll
            for (int k = 0; k < 4; k++) {
                int4 v0, v1;
                __builtin_memcpy(&v0, &wlo[k * 4], 16);
                __builtin_memcpy(&v1, &whi[k * 4], 16);
                *(int4*)(p0 + k * 8) = v0;
                *(int4*)(p1 + k * 8) = v1;
            }
        } else {
#pragma unroll
            for (int p = 0; p < 8; p++) {
                int ml = p * 16 + (tid >> 4);
                int wc = (tid & 15) * 4;
                int4 dat = *(const int4*)&LD[ml * 64 + (wc ^ (((ml >> 2) & 3) << 3))];
                int n = n0 + wc * 2;
                int part = (n >= 768) ? 1 : 0;
                int rem = n - part * 768;
                int h = rem >> 6, d = rem & 63;
                int m = m0 + ml, b = m >> 10, t = m & 1023;
                short* dst = (part == 0 ? Qb : Kb)
                             + (((size_t)b * NH + h) * TT + t) * HD + d;
                *(int4*)dst = dat;
            }
        }
    } else {
        float* LDf = (float*)smem_s;   // 64 KB
#pragma unroll
        for (int mi = 0; mi < 4; mi++)
#pragma unroll
            for (int ni = 0; ni < 4; ni++) {
                int nl = wn * 64 + ni * 16 + c;
                float bv = bias[n0 + nl];
#pragma unroll
                for (int r = 0; r < 4; r++) {
                    int ml = wm * 64 + mi * 16 + g * 4 + r;
                    LDf[ml * 128 + (nl ^ (r << 3))] = acc[mi][ni][r] + bv;
                }
            }
        __syncthreads();
#pragma unroll
        for (int p = 0; p < 8; p++) {
            int ml = p * 16 + (tid >> 4);
            int rr = (ml & 3) << 3;
            int wc4 = (tid & 15) * 8;
            const float* rp = &LDf[ml * 128 + (wc4 ^ rr)];
            float4 f0 = *(const float4*)rp;
            float4 f1 = *(const float4*)(rp + 4);
            float* dst = out + (size_t)(m0 + ml) * CC + n0 + wc4;
            *(float4*)dst = f0;
            *(float4*)(dst + 4) = f1;
        }
    }
#undef LOAD
#undef WRITE
#undef COMPUTE
}

// ---------------------------------------------------------------- flash attention
// (r13 configuration — swapped-operand S^T = mfma(K,Q), lane-local softmax,
// per-wave barrier-free LDS P-tile, V from global VT, LDS O^T epilogue)
__global__ __launch_bounds__(256)
void attn_kernel(const short* __restrict__ Qb, const short* __restrict__ Kb,
                 const short* __restrict__ VT, short* __restrict__ Ob) {
    __shared__ uint32_t Pt[4][32][32];  // 16 KB per-wave P tile, XOR-swizzled
    __shared__ uint32_t ot[128 * 32];   // 16 KB epilogue O^T transpose
    const int tid = threadIdx.x, lane = tid & 63, wid = tid >> 6;
    const int g = lane >> 4, c = lane & 15;
    const int bh = blockIdx.x, qb = 7 - (int)blockIdx.y;
    const int b = bh / NH, h = bh % NH;
    const short* Qp = Qb + (size_t)bh * TT * HD;
    const short* Kp = Kb + (size_t)bh * TT * HD;
    const short* Vp = VT + (size_t)bh * TT * HD;
    const int q0 = qb * 128 + wid * 32;
    const int sw = (c & 7) << 2;

    bf16x8 qf[2][2];
#pragma unroll
    for (int qs = 0; qs < 2; qs++)
#pragma unroll
        for (int kh = 0; kh < 2; kh++)
            qf[qs][kh] = *(const bf16x8*)(Qp + (size_t)(q0 + qs * 16 + c) * HD + kh * 32 + g * 8);

    const f32x4 zero4 = {0.f, 0.f, 0.f, 0.f};
    f32x4 o[2][4];
#pragma unroll
    for (int qs = 0; qs < 2; qs++)
#pragma unroll
        for (int dt = 0; dt < 4; dt++) o[qs][dt] = zero4;
    float mrun[2] = {-1e30f, -1e30f}, lrun[2] = {0.f, 0.f};

    const int t0max = ((q0 + 31) >> 6) << 6;
    for (int t0 = 0; t0 <= t0max; t0 += 64) {
        f32x4 st[2][4];
#pragma unroll
        for (int nt = 0; nt < 4; nt++) {
            const short* kp = Kp + (size_t)(t0 + nt * 16 + c) * HD + g * 8;
            bf16x8 k0 = *(const bf16x8*)kp;
            bf16x8 k1 = *(const bf16x8*)(kp + 32);
#pragma unroll
            for (int qs = 0; qs < 2; qs++) {
                f32x4 z = zero4;
                z = __builtin_amdgcn_mfma_f32_16x16x32_bf16(k0, qf[qs][0], z, 0, 0, 0);
                z = __builtin_amdgcn_mfma_f32_16x16x32_bf16(k1, qf[qs][1], z, 0, 0, 0);
                st[qs][nt] = z;
            }
        }
        bf16x8 vf[2][4];
#pragma unroll
        for (int blk = 0; blk < 2; blk++)
#pragma unroll
            for (int dt = 0; dt < 4; dt++)
                vf[blk][dt] = *(const bf16x8*)(Vp + (size_t)(dt * 16 + c) * TT + t0 + blk * 32 + g * 8);
        if (t0 + 63 > q0) {
#pragma unroll
            for (int qs = 0; qs < 2; qs++) {
                int q = q0 + qs * 16 + c;
#pragma unroll
                for (int nt = 0; nt < 4; nt++)
#pragma unroll
                    for (int r = 0; r < 4; r++)
                        if (t0 + nt * 16 + g * 4 + r > q) st[qs][nt][r] = -1e30f;
            }
        }
#pragma unroll
        for (int qs = 0; qs < 2; qs++) {
            float mx = st[qs][0][0];
#pragma unroll
            for (int nt = 0; nt < 4; nt++)
#pragma unroll
                for (int r = 0; r < 4; r++) mx = fmaxf(mx, st[qs][nt][r]);
            mx = fmaxf(mx, __shfl_xor(mx, 16));
            mx = fmaxf(mx, __shfl_xor(mx, 32));
            float mnew = fmaxf(mrun[qs], mx);
            float al = __expf(mrun[qs] - mnew);
            mrun[qs] = mnew;
            float sm = 0.f;
#pragma unroll
            for (int nt = 0; nt < 4; nt++)
#pragma unroll
                for (int r = 0; r < 4; r++) {
                    float e = __expf(st[qs][nt][r] - mnew);
                    st[qs][nt][r] = e;
                    sm += e;
                }
            sm += __shfl_xor(sm, 16);
            sm += __shfl_xor(sm, 32);
            lrun[qs] = lrun[qs] * al + sm;
#pragma unroll
            for (int dt = 0; dt < 4; dt++) {
                o[qs][dt][0] *= al; o[qs][dt][1] *= al;
                o[qs][dt][2] *= al; o[qs][dt][3] *= al;
            }
            int row = qs * 16 + c;
#pragma unroll
            for (int nt = 0; nt < 4; nt++) {
                uint32_t w0 = bfpack(st[qs][nt][0], st[qs][nt][1]);
                uint32_t w1 = bfpack(st[qs][nt][2], st[qs][nt][3]);
                int wa = nt * 8 + 2 * g;
                Pt[wid][row][wa ^ sw]       = w0;
                Pt[wid][row][(wa + 1) ^ sw] = w1;
            }
        }
#pragma unroll
        for (int qs = 0; qs < 2; qs++) {
            int row = qs * 16 + c;
#pragma unroll
            for (int blk = 0; blk < 2; blk++) {
                bf16x8 pf = *(const bf16x8*)&Pt[wid][row][(blk * 16 + 4 * g) ^ sw];
#pragma unroll
                for (int dt = 0; dt < 4; dt++)
                    o[qs][dt] = __builtin_amdgcn_mfma_f32_16x16x32_bf16(
                        vf[blk][dt], pf, o[qs][dt], 0, 0, 0);
            }
        }
    }

#pragma unroll
    for (int qs = 0; qs < 2; qs++) {
        float inv = 1.0f / lrun[qs];
        int ql = wid * 32 + qs * 16 + c;
#pragma unroll
        for (int dt = 0; dt < 4; dt++) {
            uint32_t w0 = bfpack(o[qs][dt][0] * inv, o[qs][dt][1] * inv);
            uint32_t w1 = bfpack(o[qs][dt][2] * inv, o[qs][dt][3] * inv);
            int jc0 = dt * 8 + 2 * g;
            int jc1 = jc0 + 1;
            ot[ql * 32 + ((((jc0 >> 2) ^ (c & 7)) << 2) | (jc0 & 3))] = w0;
            ot[ql * 32 + ((((jc1 >> 2) ^ (c & 7)) << 2) | (jc1 & 3))] = w1;
        }
    }
    __syncthreads();
#pragma unroll
    for (int p = 0; p < 4; p++) {
        int q = (tid >> 3) + 32 * p;
        int jb = tid & 7;
        const uint32_t* src = &ot[q * 32 + ((jb ^ (q & 7)) << 2)];
        int4 w = *(const int4*)src;
        *(int4*)(Ob + ((size_t)b * TT + qb * 128 + q) * CC + h * HD + jb * 8) = w;
    }
}

// ---------------------------------------------------------------- launch
extern "C" void kernel_launch(void* const* d_in, const int* in_sizes, int n_in,
                              void* d_out, int out_size, void* d_ws, size_t ws_size,
                              hipStream_t stream) {
    const float* x     = (const float*)d_in[0];
    const float* Wqkv  = (const float*)d_in[1];
    const float* bqkv  = (const float*)d_in[2];
    const float* Wproj = (const float*)d_in[3];
    const float* bproj = (const float*)d_in[4];
    // d_in[5] = mask: causal by construction, unused

    char* ws = (char*)d_ws;
    short*  WqkvT  = (short*)(ws);
    short*  WprojT = (short*)(ws + 3538944);
    float2* fc     = (float2*)(ws + 3538944 + 1179648);
    short*  Qb     = (short*)(ws + 4980736);
    short*  Kb     = (short*)(ws + 4980736 + 1 * 12582912);
    short*  VOb    = (short*)(ws + 4980736 + 2 * 12582912);  // xb, then O after attn
    short*  VbT    = (short*)(ws + 4980736 + 3 * 12582912);
    short*  xb     = VOb;
    float*  out    = (float*)d_out;

    hipLaunchKernelGGL(prep_kernel, dim3(5504), dim3(256), 0, stream,
                       x, Wqkv, Wproj, WqkvT, WprojT, xb, fc);
    hipLaunchKernelGGL((gemm_kernel<0>), dim3(18, 64), dim3(256), 0, stream,
                       xb, WqkvT, bqkv, Qb, Kb, VbT, fc, (float*)nullptr);
    hipLaunchKernelGGL(attn_kernel, dim3(96, 8), dim3(256), 0, stream, Qb, Kb, VbT, VOb);
    hipLaunchKernelGGL((gemm_kernel<1>), dim3(6, 64), dim3(256), 0, stream,
                       VOb, WprojT, bproj,
                       (short*)nullptr, (short*)nullptr, (short*)nullptr,
                       (const float2*)nullptr, out);
}